// Round 5
// baseline (40.215 us; speedup 1.0000x reference)
//
#include <hip/hip_runtime.h>

#define T_DIM 512
#define B_DIM 64
#define V_DIM 1296
#define S_DIM 30
#define LN2   0.6931471805599453f

typedef float v2f __attribute__((ext_vector_type(2)));

// DPP helper. bound_ctrl=true -> lanes with no source read 0.
template<int CTRL, bool BC>
__device__ __forceinline__ float dppf(float src, float old) {
    return __int_as_float(__builtin_amdgcn_update_dpp(
        __float_as_int(old), __float_as_int(src), CTRL, 0xF, 0xF, BC));
}

// ---------------------------------------------------------------------------
// Quad-packed scaled CTC forward chunk (32 time steps).
// Lane l (0..15): X = (alpha[4l], alpha[4l+2])  [blank positions]
//                 Y = (alpha[4l+1], alpha[4l+3]) [label positions 2l, 2l+1]
// all scaled by 2^E. LDS row layout per lane: float4 (wl0, wl1, wb, wb).
// MODE 0: chunk 0 (t==0 init). MODE 1: full. MODE 2: per-step t<len predicate.
// ---------------------------------------------------------------------------
template<int MODE>
__device__ __forceinline__ void consume_chunk(const float4* __restrict__ ringc,
                                              int c, int len, int lane, v2f S,
                                              v2f& X, v2f& Y, int& E)
{
    const int jl = lane & 15;
    float4 buf[8];
#pragma unroll
    for (int i = 0; i < 8; ++i) buf[i] = ringc[i * 16 + jl];

    float mred = 0.f;
#pragma unroll
    for (int i = 0; i < 32; ++i) {
        float4 w = buf[i & 7];
        if (i + 8 < 32) buf[i & 7] = ringc[(i + 8) * 16 + jl];

        if (MODE == 0 && i == 0) {
            bool l0 = (lane == 0);
            X = (v2f){ l0 ? ldexpf(w.z, 64) : 0.f, 0.f };   // alpha[0] = w_blank
            Y = (v2f){ l0 ? ldexpf(w.x, 64) : 0.f, 0.f };   // alpha[1] = w_lab0
            E = 64;
        } else {
            float q3m = dppf<0x111, true>(Y.y, 0.f);        // alpha[4l-1] from lane l-1
            v2f Z  = { q3m, Y.x };                          // (alpha[4l-1], alpha[4l+1])
            v2f T1 = X + Z;                                 // (q0+q3m, q2+q1)
            v2f T2 = X + Y;                                 // (q0+q1,  q2+q3)
            v2f T3 = __builtin_elementwise_fma(S, Z, T2);   // + skip terms
            v2f Wb = { w.z, w.w };
            v2f Wl = { w.x, w.y };
            v2f Xn = T1 * Wb;
            v2f Yn = T3 * Wl;
            if (MODE == 2) {
                bool act = (c * 32 + i) < len;
                X = act ? Xn : X;
                Y = act ? Yn : Y;
            } else { X = Xn; Y = Yn; }
        }

        // renorm window of 8: snapshot at step 3 (stale), reduce spread over
        // steps 4..6 (off the recurrence chain), apply at step 7 (exact 2^s).
        if ((i & 7) == 3) mred = fmaxf(fmaxf(X.x, X.y), fmaxf(Y.x, Y.y));
        if ((i & 7) == 4) mred = fmaxf(mred, dppf<0x111, true>(mred, 0.f));
        if ((i & 7) == 5) mred = fmaxf(mred, dppf<0x112, true>(mred, 0.f));
        if ((i & 7) == 6) mred = fmaxf(mred, dppf<0x114, true>(mred, 0.f));
        if ((i & 7) == 7) {
            mred = fmaxf(mred, dppf<0x118, true>(mred, 0.f));  // lane15 = max(0..15)
            int e15 = (__builtin_amdgcn_readlane(__float_as_int(mred), 15) >> 23) & 0xFF;
            int s = 191 - e15;                               // recenter max at 2^64
            X = (v2f){ ldexpf(X.x, s), ldexpf(X.y, s) };
            Y = (v2f){ ldexpf(Y.x, s), ldexpf(Y.y, s) };
            E += s;
        }
    }
}

struct PReg { float a, b, c; };   // lp[lab 2q], lp[lab 2q+1], lp[blank]

__device__ __forceinline__ PReg load_rows(const float* __restrict__ lpb,
                                          int k, int r, int lab0, int lab1)
{
    const float* row = lpb + (size_t)(k * 32 + r) * (B_DIM * V_DIM);
    PReg x;
    x.a = row[lab0];
    x.b = row[lab1];
    x.c = row[0];
    return x;
}

__device__ __forceinline__ void write_chunk(float4* __restrict__ ring, int k, int p,
                                            int q, const PReg& x)
{
    float wz = __expf(x.c);
    float wx = (q < 15) ? __expf(x.a) : 0.f;   // lane15 labels don't exist
    float wy = (q < 15) ? __expf(x.b) : 0.f;
    ring[(size_t)(k & 3) * 512 + p] = make_float4(wx, wy, wz, wz);
}

__global__ __launch_bounds__(576)
void ctc_fused_kernel(const float* __restrict__ log_probs,
                      const int*   __restrict__ targets,
                      const int*   __restrict__ input_lengths,
                      const int*   __restrict__ target_lengths,
                      float*       __restrict__ losses,
                      unsigned*    __restrict__ counter,
                      float*       __restrict__ out)
{
    __shared__ float4 ring[4 * 512];                 // 4-chunk ring, 32 KB
    const int  b    = blockIdx.x;
    const int  tid  = threadIdx.x;
    const int  len  = input_lengths[b];
    const bool prod = (tid < 512);

    // producer state
    const int q = tid & 15;                          // lane-slot within row
    const int r = (tid & 511) >> 4;                  // t-row within chunk (0..31)
    int lab0 = 0, lab1 = 0;
    PReg rA = {0,0,0}, rB = {0,0,0};
    const float* lpb = log_probs + (size_t)b * V_DIM;

    // scanner state
    const int lane = tid - 512;
    v2f X = {0.f, 0.f}, Y = {0.f, 0.f}, S = {0.f, 0.f};
    int E = 0;

    if (prod) {
        int i0 = b * S_DIM + ((2 * q     < S_DIM) ? 2 * q     : 0);
        int i1 = b * S_DIM + ((2 * q + 1 < S_DIM) ? 2 * q + 1 : 0);
        lab0 = targets[i0];
        lab1 = targets[i1];
        // chunks 0..2 staged directly; register-lead for chunks 3,4
        PReg t0 = load_rows(lpb, 0, r, lab0, lab1);
        PReg t1 = load_rows(lpb, 1, r, lab0, lab1);
        PReg t2 = load_rows(lpb, 2, r, lab0, lab1);
        rA = load_rows(lpb, 3, r, lab0, lab1);
        rB = load_rows(lpb, 4, r, lab0, lab1);
        write_chunk(ring, 0, tid, q, t0);
        write_chunk(ring, 1, tid, q, t1);
        write_chunk(ring, 2, tid, q, t2);
    } else {
        int lq = lane & 15;
        float s0 = 0.f, s1 = 0.f;
        if (lq < 15) {
            int k0 = 2 * lq;
            int tc = targets[b * S_DIM + k0];
            int tp = (k0 > 0) ? targets[b * S_DIM + k0 - 1] : -1;  // -1 = blank
            s0 = (tc != tp) ? 1.f : 0.f;
            int tn = targets[b * S_DIM + k0 + 1];
            s1 = (tn != tc) ? 1.f : 0.f;
        }
        S = (v2f){ s0, s1 };
    }
    __syncthreads();

    for (int c = 0; c < 16; ++c) {
        if (prod) {
            if (c < 13) write_chunk(ring, c + 3, tid, q, rA);   // loaded at iter c-2
            PReg nl = {0,0,0};
            if (c < 11) nl = load_rows(lpb, c + 5, r, lab0, lab1);
            rA = rB; rB = nl;
        } else {
            const float4* ringc = &ring[(size_t)(c & 3) * 512];
            if (c == 0)                   consume_chunk<0>(ringc, c, len, lane, S, X, Y, E);
            else if ((c + 1) * 32 <= len) consume_chunk<1>(ringc, c, len, lane, S, X, Y, E);
            else if (c * 32 < len)        consume_chunk<2>(ringc, c, len, lane, S, X, Y, E);
        }
        __syncthreads();
    }

    if (!prod) {
        // alpha[2*tl] and alpha[2*tl-1]; tl==30 -> positions 60 (lane15,q0)
        // and 59 (lane14,q3). Selection is wave-uniform.
        int tl   = target_lengths[b];
        int pB_p = 2 * tl, pL_p = 2 * tl - 1;
        float vB = (pB_p & 2) ? ((pB_p & 1) ? Y.y : X.y) : ((pB_p & 1) ? Y.x : X.x);
        float vL = (pL_p & 2) ? ((pL_p & 1) ? Y.y : X.y) : ((pL_p & 1) ? Y.x : X.x);
        float pB = __shfl(vB, pB_p >> 2);
        float pL = __shfl(vL, pL_p >> 2);
        if (lane == 0) {
            float loss = -LN2 * (__builtin_amdgcn_logf(pB + pL) - (float)E);
            if (!(loss < 1e29f)) loss = 0.f;         // zero_infinity (inf/NaN)
            losses[b] = loss / (float)tl;
            __threadfence();                          // release per-block loss
            unsigned old = atomicAdd(counter, 1u);    // device-scope
            if (old == 63u) {                         // last block reduces
                __threadfence();                      // acquire
                float sum = 0.f;
                for (int i = 0; i < B_DIM; ++i)
                    sum += ((volatile const float*)losses)[i];
                out[0] = sum * (1.f / (float)B_DIM);
            }
        }
    }
}

extern "C" void kernel_launch(void* const* d_in, const int* in_sizes, int n_in,
                              void* d_out, int out_size, void* d_ws, size_t ws_size,
                              hipStream_t stream)
{
    const float* log_probs      = (const float*)d_in[0];
    const int*   targets        = (const int*)  d_in[1];
    const int*   input_lengths  = (const int*)  d_in[2];
    const int*   target_lengths = (const int*)  d_in[3];
    float*       out            = (float*)d_out;
    float*       losses         = (float*)d_ws;                    // 64 floats
    unsigned*    counter        = (unsigned*)((char*)d_ws + 256);  // own line

    hipMemsetAsync(counter, 0, sizeof(unsigned), stream);          // capturable
    hipLaunchKernelGGL(ctc_fused_kernel, dim3(B_DIM), dim3(576), 0, stream,
                       log_probs, targets, input_lengths, target_lengths,
                       losses, counter, out);
}

// Round 6
// 35.164 us; speedup vs baseline: 1.1437x; 1.1437x over previous
//
#include <hip/hip_runtime.h>

#define T_DIM 512
#define B_DIM 64
#define V_DIM 1296
#define S_DIM 30
#define LN2   0.6931471805599453f

typedef float v2f __attribute__((ext_vector_type(2)));

// DPP helper. bound_ctrl=true -> lanes with no source read 0.
template<int CTRL, bool BC>
__device__ __forceinline__ float dppf(float src, float old) {
    return __int_as_float(__builtin_amdgcn_update_dpp(
        __float_as_int(old), __float_as_int(src), CTRL, 0xF, 0xF, BC));
}

// ---------------------------------------------------------------------------
// Quad-packed scaled CTC forward chunk (32 time steps).
// Lane l (0..15): X = (alpha[4l], alpha[4l+2])  [blank positions]
//                 Y = (alpha[4l+1], alpha[4l+3]) [label positions 2l, 2l+1]
// all scaled by 2^E. LDS row layout per lane: float4 (wl0, wl1, wb, wb).
// MODE 0: chunk 0 (t==0 init). MODE 1: full. MODE 2: per-step t<len predicate.
// ---------------------------------------------------------------------------
template<int MODE>
__device__ __forceinline__ void consume_chunk(const float4* __restrict__ ringc,
                                              int c, int len, int lane, v2f S,
                                              v2f& X, v2f& Y, int& E)
{
    const int jl = lane & 15;
    float4 buf[8];
#pragma unroll
    for (int i = 0; i < 8; ++i) buf[i] = ringc[i * 16 + jl];

    float mred = 0.f;
#pragma unroll
    for (int i = 0; i < 32; ++i) {
        float4 w = buf[i & 7];
        if (i + 8 < 32) buf[i & 7] = ringc[(i + 8) * 16 + jl];

        if (MODE == 0 && i == 0) {
            bool l0 = (lane == 0);
            X = (v2f){ l0 ? ldexpf(w.z, 64) : 0.f, 0.f };   // alpha[0] = w_blank
            Y = (v2f){ l0 ? ldexpf(w.x, 64) : 0.f, 0.f };   // alpha[1] = w_lab0
            E = 64;
        } else {
            float q3m = dppf<0x111, true>(Y.y, 0.f);        // alpha[4l-1] from lane l-1
            v2f Z  = { q3m, Y.x };                          // (alpha[4l-1], alpha[4l+1])
            v2f T1 = X + Z;                                 // (q0+q3m, q2+q1)
            v2f T2 = X + Y;                                 // (q0+q1,  q2+q3)
            v2f T3 = __builtin_elementwise_fma(S, Z, T2);   // + skip terms
            v2f Wb = { w.z, w.w };
            v2f Wl = { w.x, w.y };
            v2f Xn = T1 * Wb;
            v2f Yn = T3 * Wl;
            if (MODE == 2) {
                bool act = (c * 32 + i) < len;
                X = act ? Xn : X;
                Y = act ? Yn : Y;
            } else { X = Xn; Y = Yn; }
        }

        // renorm window of 8: snapshot at step 3 (stale), reduce spread over
        // steps 4..6 (off the recurrence chain), apply at step 7 (exact 2^s).
        if ((i & 7) == 3) mred = fmaxf(fmaxf(X.x, X.y), fmaxf(Y.x, Y.y));
        if ((i & 7) == 4) mred = fmaxf(mred, dppf<0x111, true>(mred, 0.f));
        if ((i & 7) == 5) mred = fmaxf(mred, dppf<0x112, true>(mred, 0.f));
        if ((i & 7) == 6) mred = fmaxf(mred, dppf<0x114, true>(mred, 0.f));
        if ((i & 7) == 7) {
            mred = fmaxf(mred, dppf<0x118, true>(mred, 0.f));  // lane15 = max(0..15)
            int e15 = (__builtin_amdgcn_readlane(__float_as_int(mred), 15) >> 23) & 0xFF;
            int s = 191 - e15;                               // recenter max at 2^64
            X = (v2f){ ldexpf(X.x, s), ldexpf(X.y, s) };
            Y = (v2f){ ldexpf(Y.x, s), ldexpf(Y.y, s) };
            E += s;
        }
    }
}

struct PReg { float a, b, c; };   // lp[lab 2q], lp[lab 2q+1], lp[blank]

__device__ __forceinline__ PReg load_rows(const float* __restrict__ lpb,
                                          int k, int r, int lab0, int lab1)
{
    const float* row = lpb + (size_t)(k * 32 + r) * (B_DIM * V_DIM);
    PReg x;
    x.a = row[lab0];
    x.b = row[lab1];
    x.c = row[0];
    return x;
}

__device__ __forceinline__ void write_chunk(float4* __restrict__ ring, int k, int p,
                                            int q, const PReg& x)
{
    float wz = __expf(x.c);
    float wx = (q < 15) ? __expf(x.a) : 0.f;   // lane15 labels don't exist
    float wy = (q < 15) ? __expf(x.b) : 0.f;
    ring[(size_t)(k & 3) * 512 + p] = make_float4(wx, wy, wz, wz);
}

__global__ __launch_bounds__(576)
void ctc_fused_kernel(const float* __restrict__ log_probs,
                      const int*   __restrict__ targets,
                      const int*   __restrict__ input_lengths,
                      const int*   __restrict__ target_lengths,
                      float*       __restrict__ losses,
                      unsigned*    __restrict__ counter,
                      float*       __restrict__ out)
{
    __shared__ float4 ring[4 * 512];                 // 4-chunk ring, 32 KB
    const int  b    = blockIdx.x;
    const int  tid  = threadIdx.x;
    const int  len  = input_lengths[b];
    const bool prod = (tid < 512);                   // waves 0-7 produce, wave 8 scans

    // producer state
    const int q = tid & 15;                          // lane-slot within row
    const int r = (tid & 511) >> 4;                  // t-row within chunk (0..31)
    int lab0 = 0, lab1 = 0;
    PReg rA = {0,0,0}, rB = {0,0,0};
    const float* lpb = log_probs + (size_t)b * V_DIM;

    // scanner state
    const int lane = tid - 512;
    v2f X = {0.f, 0.f}, Y = {0.f, 0.f}, S = {0.f, 0.f};
    int E = 0;

    if (prod) {
        int i0 = b * S_DIM + ((2 * q     < S_DIM) ? 2 * q     : 0);
        int i1 = b * S_DIM + ((2 * q + 1 < S_DIM) ? 2 * q + 1 : 0);
        lab0 = targets[i0];
        lab1 = targets[i1];
        PReg t0 = load_rows(lpb, 0, r, lab0, lab1);
        PReg t1 = load_rows(lpb, 1, r, lab0, lab1);
        PReg t2 = load_rows(lpb, 2, r, lab0, lab1);
        rA = load_rows(lpb, 3, r, lab0, lab1);       // register lead, 2 chunks deep
        rB = load_rows(lpb, 4, r, lab0, lab1);
        write_chunk(ring, 0, tid, q, t0);
        write_chunk(ring, 1, tid, q, t1);
        write_chunk(ring, 2, tid, q, t2);
        // drain ONLY the LDS queue; rA/rB global loads stay in flight
        asm volatile("s_waitcnt lgkmcnt(0)" ::: "memory");
    } else {
        int lq = lane & 15;
        float s0 = 0.f, s1 = 0.f;
        if (lq < 15) {
            int k0 = 2 * lq;
            int tc = targets[b * S_DIM + k0];
            int tp = (k0 > 0) ? targets[b * S_DIM + k0 - 1] : -1;  // -1 = blank
            s0 = (tc != tp) ? 1.f : 0.f;
            int tn = targets[b * S_DIM + k0 + 1];
            s1 = (tn != tc) ? 1.f : 0.f;
        }
        S = (v2f){ s0, s1 };
    }
    __builtin_amdgcn_s_barrier();                    // raw barrier: NO vmcnt drain
    __builtin_amdgcn_sched_barrier(0);

    for (int c = 0; c < 16; ++c) {
        if (prod) {
            if (c < 13) write_chunk(ring, c + 3, tid, q, rA);   // loaded 2 iters ago
            PReg nl = {0,0,0};
            if (c < 11) nl = load_rows(lpb, c + 5, r, lab0, lab1);
            rA = rB; rB = nl;
            asm volatile("s_waitcnt lgkmcnt(0)" ::: "memory");  // LDS-only drain
        } else {
            const float4* ringc = &ring[(size_t)(c & 3) * 512];
            if (c == 0)                   consume_chunk<0>(ringc, c, len, lane, S, X, Y, E);
            else if ((c + 1) * 32 <= len) consume_chunk<1>(ringc, c, len, lane, S, X, Y, E);
            else if (c * 32 < len)        consume_chunk<2>(ringc, c, len, lane, S, X, Y, E);
        }
        __builtin_amdgcn_s_barrier();
        __builtin_amdgcn_sched_barrier(0);
    }

    if (!prod) {
        // alpha[2*tl] (pos 60: lane15, X.x) and alpha[2*tl-1] (pos 59: lane14, Y.y)
        int tl   = target_lengths[b];
        int pB_p = 2 * tl, pL_p = 2 * tl - 1;
        float vB = (pB_p & 2) ? ((pB_p & 1) ? Y.y : X.y) : ((pB_p & 1) ? Y.x : X.x);
        float vL = (pL_p & 2) ? ((pL_p & 1) ? Y.y : X.y) : ((pL_p & 1) ? Y.x : X.x);
        float pB = __shfl(vB, pB_p >> 2);
        float pL = __shfl(vL, pL_p >> 2);
        float loss = -LN2 * (__builtin_amdgcn_logf(pB + pL) - (float)E);
        if (!(loss < 1e29f)) loss = 0.f;             // zero_infinity (inf/NaN)
        loss /= (float)tl;

        unsigned old = 0;
        if (lane == 0) {
            losses[b] = loss;
            __threadfence();                         // release per-block loss
            old = atomicAdd(counter, 1u);            // device-scope
        }
        old = __shfl(old, 0);
        if (old == 63u) {                            // last block reduces, LANE-PARALLEL
            __threadfence();                         // acquire (all lanes)
            float v = ((volatile const float*)losses)[lane];   // 64 parallel loads
#pragma unroll
            for (int off = 32; off >= 1; off >>= 1)
                v += __shfl_xor(v, off);
            if (lane == 0) out[0] = v * (1.f / (float)B_DIM);
        }
    }
}

extern "C" void kernel_launch(void* const* d_in, const int* in_sizes, int n_in,
                              void* d_out, int out_size, void* d_ws, size_t ws_size,
                              hipStream_t stream)
{
    const float* log_probs      = (const float*)d_in[0];
    const int*   targets        = (const int*)  d_in[1];
    const int*   input_lengths  = (const int*)  d_in[2];
    const int*   target_lengths = (const int*)  d_in[3];
    float*       out            = (float*)d_out;
    float*       losses         = (float*)d_ws;                    // 64 floats
    unsigned*    counter        = (unsigned*)((char*)d_ws + 256);  // own cache line

    hipMemsetAsync(counter, 0, sizeof(unsigned), stream);          // capturable
    hipLaunchKernelGGL(ctc_fused_kernel, dim3(B_DIM), dim3(576), 0, stream,
                       log_probs, targets, input_lengths, target_lengths,
                       losses, counter, out);
}